// Round 1
// baseline (131.564 us; speedup 1.0000x reference)
//
#include <hip/hip_runtime.h>

#define K_CL 1024
#define B_RS 4
#define Q_MIN_F 0.1f
#define S_B_F 1.0f
#define BETA_EPS_F 0.001f
#define LSE_EPS_F 0.001f
#define ACC (27 * K_CL + 8)
// accs layout (floats at w+ACC): [0..B) att_sum, [B..2B) rep_sum, [2B..3B) obj_cnt,
// [3B..4B) obj_pen, [4B..5B) noise_cnt, [5B..6B) noise_sum

__device__ __forceinline__ unsigned fkey(float f) {
    unsigned u = __float_as_uint(f);
    return ((int)u < 0) ? ~u : (u | 0x80000000u);
}
__device__ __forceinline__ float fdec(unsigned k) {
    unsigned u = ((int)k < 0) ? (k & 0x7fffffffu) : ~k;
    return __uint_as_float(u);
}
__device__ __forceinline__ int ptrs_of(int i, const int* rs) {
    int r = 0;
#pragma unroll
    for (int j = 1; j < B_RS; ++j) r += (i >= rs[j]) ? 1 : 0;
    return r;
}

__global__ void k_init(float* w) {
    int t = blockIdx.x * blockDim.x + threadIdx.x;
    if (t < K_CL) {
        ((unsigned*)w)[t] = 0u;                 // seg_max keys (key(-inf) ~ 0)
        ((unsigned*)(w + K_CL))[t] = 0u;        // N_k
        ((int*)(w + 2 * K_CL))[t] = -1;         // alpha_idx
        w[3 * K_CL + t] = 0.f;                  // sum_b
        w[4 * K_CL + t] = 0.f;                  // p_sum
        w[5 * K_CL + t] = 0.f;                  // lse_sum
    }
    if (t < 6 * B_RS) w[ACC + t] = 0.f;
}

__global__ __launch_bounds__(256) void k_p1(const float* __restrict__ beta,
                                            const int* __restrict__ asso,
                                            const int* __restrict__ rs,
                                            float* __restrict__ w, int N) {
    __shared__ float s_nsum[B_RS];
    __shared__ float s_ncnt[B_RS];
    int t = threadIdx.x;
    if (t < B_RS) { s_nsum[t] = 0.f; s_ncnt[t] = 0.f; }
    __syncthreads();
    int i = blockIdx.x * 256 + t;
    if (i < N) {
        float b = beta[i];
        int a = asso[i];
        if (a >= 0) {
            atomicMax((unsigned*)w + a, fkey(b));
            atomicAdd((unsigned*)(w + K_CL) + a, 1u);
            atomicAdd(w + 3 * K_CL + a, b);
            float bc = fminf(fmaxf(b, 0.f), 1.f - BETA_EPS_F);
            float at = atanhf(bc);
            atomicAdd(w + 4 * K_CL + a, fmaxf(at * at, 1e-6f));
        } else {
            int r = ptrs_of(i, rs);
            atomicAdd(&s_nsum[r], b);
            atomicAdd(&s_ncnt[r], 1.f);
        }
    }
    __syncthreads();
    if (t < B_RS) {
        if (s_ncnt[t] != 0.f) {
            atomicAdd(w + ACC + 4 * B_RS + t, s_ncnt[t]);
            atomicAdd(w + ACC + 5 * B_RS + t, s_nsum[t]);
        }
    }
}

__global__ __launch_bounds__(256) void k_p2(const float* __restrict__ beta,
                                            const int* __restrict__ asso,
                                            float* __restrict__ w, int N) {
    int i = blockIdx.x * 256 + threadIdx.x;
    if (i >= N) return;
    int a = asso[i];
    if (a < 0) return;
    float b = beta[i];
    unsigned mk = fkey(b);
    unsigned sk = ((unsigned*)w)[a];
    if (mk == sk) atomicMax((int*)(w + 2 * K_CL) + a, i);
    float m = fdec(sk);
    atomicAdd(w + 5 * K_CL + a, expf((b - m) / LSE_EPS_F));
}

__global__ __launch_bounds__(1024) void k_p3(const float* __restrict__ beta,
                                             const float* __restrict__ coords,
                                             const int* __restrict__ rs,
                                             float* __restrict__ w) {
    int k = threadIdx.x;
    unsigned sk = ((unsigned*)w)[k];
    unsigned nk = ((unsigned*)(w + K_CL))[k];
    int aidx = ((int*)(w + 2 * K_CL))[k];
    bool ov = nk > 0u;
    int a = aidx > 0 ? aidx : 0;
    float x[8];
#pragma unroll
    for (int j = 0; j < 8; ++j) x[j] = coords[a * 8 + j];
    float ba = beta[a];
    float bca = fminf(fmaxf(ba, 0.f), 1.f - BETA_EPS_F);
    float ata = atanhf(bca);
    float qa = ov ? (ata * ata + Q_MIN_F) : 0.f;
    int orr = ptrs_of(a, rs);
    float cf = qa / fmaxf((float)nk, 1.f);
    w[6 * K_CL + k] = qa;
    w[7 * K_CL + k] = cf;
    ((int*)(w + 8 * K_CL))[k] = orr;
    ((float4*)(w + 9 * K_CL))[k] = make_float4(x[0], x[1], x[2], x[3]);
    ((float4*)(w + 13 * K_CL))[k] = make_float4(x[4], x[5], x[6], x[7]);
    // beta penalty
    float m = ov ? fdec(sk) : 0.f;
    float lse = m + LSE_EPS_F * logf(w[5 * K_CL + k] + 1e-30f);
    float sb = fminf(fmaxf(w[3 * K_CL + k], 0.f), 1.f);
    float bpen = 1.f - lse + (1.f - sb);
    if (ov) {
        atomicAdd(w + ACC + 2 * B_RS + orr, 1.f);
        atomicAdd(w + ACC + 3 * B_RS + orr, bpen);
    }
    // stable (ascending-k) compaction of valid clusters by row
    int key = ov ? orr : B_RS;
    __shared__ int wcnt[16][B_RS];
    __shared__ int woff[16][B_RS];
    __shared__ int rbase[B_RS + 1];
    int wv = k >> 6, ln = k & 63;
    unsigned long long myball = 0ULL;
#pragma unroll
    for (int r = 0; r < B_RS; ++r) {
        unsigned long long bl = __ballot(key == r);
        if (ln == 0) wcnt[wv][r] = __popcll(bl);
        if (key == r) myball = bl;
    }
    __syncthreads();
    if (k == 0) {
        int base = 0;
        for (int r = 0; r < B_RS; ++r) {
            rbase[r] = base;
            for (int wq = 0; wq < 16; ++wq) { woff[wq][r] = base; base += wcnt[wq][r]; }
        }
        rbase[B_RS] = base;
    }
    __syncthreads();
    if (key < B_RS) {
        int slot = woff[wv][key] + __popcll(myball & ((1ULL << ln) - 1ULL));
        ((float4*)(w + 17 * K_CL))[slot] = make_float4(x[0], x[1], x[2], x[3]);
        ((float4*)(w + 21 * K_CL))[slot] = make_float4(x[4], x[5], x[6], x[7]);
        float ck2 = 0.f;
#pragma unroll
        for (int j = 0; j < 8; ++j) ck2 += x[j] * x[j];
        ((float2*)(w + 25 * K_CL))[slot] = make_float2(ck2, cf);
    }
    if (k <= B_RS) ((int*)(w + 27 * K_CL))[k] = rbase[k];
}

__global__ __launch_bounds__(256) void k_p4(const float* __restrict__ beta,
                                            const float* __restrict__ coords,
                                            const int* __restrict__ asso,
                                            const int* __restrict__ rs,
                                            float* __restrict__ w,
                                            float* __restrict__ out, int N) {
    __shared__ float4 sx0[K_CL];
    __shared__ float4 sx1[K_CL];
    __shared__ float2 scc[K_CL];
    __shared__ int soff[B_RS + 1];
    __shared__ float sa[B_RS], sr[B_RS];
    int t = threadIdx.x;
    for (int j = t; j < K_CL; j += 256) {
        sx0[j] = ((const float4*)(w + 17 * K_CL))[j];
        sx1[j] = ((const float4*)(w + 21 * K_CL))[j];
        scc[j] = ((const float2*)(w + 25 * K_CL))[j];
    }
    if (t <= B_RS) soff[t] = ((const int*)(w + 27 * K_CL))[t];
    if (t < B_RS) { sa[t] = 0.f; sr[t] = 0.f; }
    __syncthreads();
    int i = blockIdx.x * 256 + t;
    if (i < N) {
        float b = beta[i];
        int a0 = asso[i];
        bool valid = a0 >= 0;
        int kk = valid ? a0 : 0;
        int r = ptrs_of(i, rs);
        float4 c0 = ((const float4*)coords)[i * 2];
        float4 c1 = ((const float4*)coords)[i * 2 + 1];
        float bc = fminf(fmaxf(b, 0.f), 1.f - BETA_EPS_F);
        float at = atanhf(bc);
        float at2 = at * at;
        float q = at2 + Q_MIN_F;
        float cn2 = c0.x * c0.x + c0.y * c0.y + c0.z * c0.z + c0.w * c0.w +
                    c1.x * c1.x + c1.y * c1.y + c1.z * c1.z + c1.w * c1.w;
        // attraction (uses direct squared differences, as reference)
        float4 xk0 = ((const float4*)(w + 9 * K_CL))[kk];
        float4 xk1 = ((const float4*)(w + 13 * K_CL))[kk];
        float qak = w[6 * K_CL + kk];
        float d0 = c0.x - xk0.x, d1 = c0.y - xk0.y, d2 = c0.z - xk0.z, d3 = c0.w - xk0.w;
        float d4 = c1.x - xk1.x, d5 = c1.y - xk1.y, d6 = c1.z - xk1.z, d7 = c1.w - xk1.w;
        float dsq_att = d0 * d0 + d1 * d1 + d2 * d2 + d3 * d3 +
                        d4 * d4 + d5 * d5 + d6 * d6 + d7 * d7;
        float att = valid ? q * qak * dsq_att : 0.f;
        // repulsion: loop over this row's valid clusters (compacted, in LDS)
        int js = soff[r], je = soff[r + 1];
        float acc = 0.f;
        for (int j = js; j < je; ++j) {
            float4 y0 = sx0[j];
            float4 y1 = sx1[j];
            float2 cc = scc[j];
            float dot = c0.x * y0.x + c0.y * y0.y + c0.z * y0.z + c0.w * y0.w +
                        c1.x * y1.x + c1.y * y1.y + c1.z * y1.z + c1.w * y1.w;
            float dsq = fmaxf(cn2 + cc.x - 2.f * dot, 0.f);
            float v = 1.f - sqrtf(dsq + 1e-6f);
            acc += fmaxf(v, 0.f) * cc.y;
        }
        // subtract own-cluster contribution (mask excludes it)
        if (valid) {
            int ork = ((const int*)(w + 8 * K_CL))[kk];
            if (ork == r) {
                float ck2 = xk0.x * xk0.x + xk0.y * xk0.y + xk0.z * xk0.z + xk0.w * xk0.w +
                            xk1.x * xk1.x + xk1.y * xk1.y + xk1.z * xk1.z + xk1.w * xk1.w;
                float dotk = c0.x * xk0.x + c0.y * xk0.y + c0.z * xk0.z + c0.w * xk0.w +
                             c1.x * xk1.x + c1.y * xk1.y + c1.z * xk1.z + c1.w * xk1.w;
                float dsqk = fmaxf(cn2 + ck2 - 2.f * dotk, 0.f);
                float vk = 1.f - sqrtf(dsqk + 1e-6f);
                acc -= fmaxf(vk, 0.f) * w[7 * K_CL + kk];
            }
        }
        float rep = q * acc;
        // pl
        float psum = w[4 * K_CL + kk];
        float ocnt = w[ACC + 2 * B_RS + r];
        float pl = valid ? fmaxf(at2, 1e-6f) / fmaxf(psum, 1e-6f) : 0.f;
        pl = pl / fmaxf(ocnt, 1.f) * (1.f / B_RS);
        out[3 + i] = pl;
        out[3 + N + i] = att + rep;
        atomicAdd(&sa[r], att);
        atomicAdd(&sr[r], rep);
    }
    __syncthreads();
    if (t < B_RS) {
        atomicAdd(w + ACC + t, sa[t]);
        atomicAdd(w + ACC + B_RS + t, sr[t]);
    }
}

__global__ void k_p5(const int* __restrict__ rs, const float* __restrict__ w,
                     float* __restrict__ out) {
    if (threadIdx.x == 0 && blockIdx.x == 0) {
        float lv = 0.f, lr = 0.f, lb = 0.f;
        for (int r = 0; r < B_RS; ++r) {
            float len = (float)(rs[r + 1] - rs[r]);
            lv += w[ACC + r] / len;
            lr += w[ACC + B_RS + r] / len;
            float oc = w[ACC + 2 * B_RS + r];
            float op = w[ACC + 3 * B_RS + r];
            float nc = w[ACC + 4 * B_RS + r];
            float ns = w[ACC + 5 * B_RS + r];
            lb += op / fmaxf(oc, 1.f) + S_B_F * (ns / fmaxf(nc, 1.f));
        }
        out[0] = lv * (1.f / B_RS);
        out[1] = lr * (1.f / B_RS);
        out[2] = lb * (1.f / B_RS);
    }
}

extern "C" void kernel_launch(void* const* d_in, const int* in_sizes, int n_in,
                              void* d_out, int out_size, void* d_ws, size_t ws_size,
                              hipStream_t stream) {
    const float* beta = (const float*)d_in[0];
    const float* coords = (const float*)d_in[1];
    const int* asso = (const int*)d_in[2];
    const int* rs = (const int*)d_in[3];
    int N = in_sizes[0];
    float* w = (float*)d_ws;
    float* out = (float*)d_out;
    int nb = (N + 255) / 256;
    hipLaunchKernelGGL(k_init, dim3(1), dim3(1024), 0, stream, w);
    hipLaunchKernelGGL(k_p1, dim3(nb), dim3(256), 0, stream, beta, asso, rs, w, N);
    hipLaunchKernelGGL(k_p2, dim3(nb), dim3(256), 0, stream, beta, asso, w, N);
    hipLaunchKernelGGL(k_p3, dim3(1), dim3(1024), 0, stream, beta, coords, rs, w);
    hipLaunchKernelGGL(k_p4, dim3(nb), dim3(256), 0, stream, beta, coords, asso, rs, w, out, N);
    hipLaunchKernelGGL(k_p5, dim3(1), dim3(64), 0, stream, rs, w, out);
}

// Round 2
// 106.243 us; speedup vs baseline: 1.2383x; 1.2383x over previous
//
#include <hip/hip_runtime.h>

#define K_CL 1024
#define B_RS 4
#define KPB 256
#define Q_MIN_F 0.1f
#define S_B_F 1.0f
#define BETA_EPS_F 0.001f
#define LSE_EPS_F 0.001f
#define ACC (27 * K_CL + 8)
#define CCH 8
#define P4_PPB 512

__device__ __forceinline__ unsigned fkey(float f) {
    unsigned u = __float_as_uint(f);
    return ((int)u < 0) ? ~u : (u | 0x80000000u);
}
__device__ __forceinline__ float fdec(unsigned k) {
    unsigned u = ((int)k < 0) ? (k & 0x7fffffffu) : ~k;
    return __uint_as_float(u);
}

__global__ __launch_bounds__(1024) void k_init(float* w) {
    int t = threadIdx.x;
    ((unsigned*)w)[t] = 0u;
    ((unsigned*)(w + K_CL))[t] = 0u;
    ((int*)(w + 2 * K_CL))[t] = -1;
    w[3 * K_CL + t] = 0.f;
    w[4 * K_CL + t] = 0.f;
    w[5 * K_CL + t] = 0.f;
    if (t < 24) w[ACC + t] = 0.f;
}

// ---- P1: seg_max key, N_k, sum_b, p_sum, noise bins (LDS-aggregated) ----
__global__ __launch_bounds__(256) void k_p1(const float* __restrict__ beta,
                                            const int* __restrict__ asso,
                                            const int* __restrict__ rs,
                                            float* __restrict__ w, int N) {
    __shared__ unsigned s_key[512];
    __shared__ unsigned s_cnt[512];
    __shared__ float s_sb[512];
    __shared__ float s_sp[512];
    __shared__ float s_nsum[B_RS], s_ncnt[B_RS];
    int t = threadIdx.x;
    for (int j = t; j < 512; j += 256) { s_key[j] = 0u; s_cnt[j] = 0u; s_sb[j] = 0.f; s_sp[j] = 0.f; }
    if (t < B_RS) { s_nsum[t] = 0.f; s_ncnt[t] = 0.f; }
    int rs1 = rs[1], rs2 = rs[2], rs3 = rs[3];
    int base_i = blockIdx.x * 512;
    int r0 = (base_i >= rs1) + (base_i >= rs2) + (base_i >= rs3);
    int cbase = r0 * KPB;
    __syncthreads();
    int i0 = base_i + 2 * t;
#pragma unroll
    for (int p = 0; p < 2; ++p) {
        int i = i0 + p;
        if (i >= N) break;
        float b = beta[i];
        int a = asso[i];
        if (a >= 0) {
            float bc = fminf(fmaxf(b, 0.f), 1.f - BETA_EPS_F);
            float at = atanhf(bc);
            float pv = fmaxf(at * at, 1e-6f);
            int idx = a - cbase;
            if ((unsigned)idx < 512u) {
                atomicMax(&s_key[idx], fkey(b));
                atomicAdd(&s_cnt[idx], 1u);
                atomicAdd(&s_sb[idx], b);
                atomicAdd(&s_sp[idx], pv);
            } else {
                atomicMax((unsigned*)w + a, fkey(b));
                atomicAdd((unsigned*)(w + K_CL) + a, 1u);
                atomicAdd(w + 3 * K_CL + a, b);
                atomicAdd(w + 4 * K_CL + a, pv);
            }
        } else {
            int r = (i >= rs1) + (i >= rs2) + (i >= rs3);
            atomicAdd(&s_nsum[r], b);
            atomicAdd(&s_ncnt[r], 1.f);
        }
    }
    __syncthreads();
    for (int j = t; j < 512; j += 256) {
        unsigned c = s_cnt[j];
        int a = cbase + j;
        if (c && a < K_CL) {
            atomicMax((unsigned*)w + a, s_key[j]);
            atomicAdd((unsigned*)(w + K_CL) + a, c);
            atomicAdd(w + 3 * K_CL + a, s_sb[j]);
            atomicAdd(w + 4 * K_CL + a, s_sp[j]);
        }
    }
    if (t < B_RS && s_ncnt[t] != 0.f) {
        atomicAdd(w + ACC + 4 * B_RS + t, s_ncnt[t]);
        atomicAdd(w + ACC + 5 * B_RS + t, s_nsum[t]);
    }
}

// ---- P2: alpha idx (argmax tie->max idx), LSE sums (LDS-aggregated) ----
__global__ __launch_bounds__(256) void k_p2(const float* __restrict__ beta,
                                            const int* __restrict__ asso,
                                            const int* __restrict__ rs,
                                            float* __restrict__ w, int N) {
    __shared__ float s_lse[512];
    __shared__ int s_idx[512];
    int t = threadIdx.x;
    for (int j = t; j < 512; j += 256) { s_lse[j] = 0.f; s_idx[j] = -1; }
    int rs1 = rs[1], rs2 = rs[2], rs3 = rs[3];
    int base_i = blockIdx.x * 512;
    int r0 = (base_i >= rs1) + (base_i >= rs2) + (base_i >= rs3);
    int cbase = r0 * KPB;
    __syncthreads();
    int i0 = base_i + 2 * t;
#pragma unroll
    for (int p = 0; p < 2; ++p) {
        int i = i0 + p;
        if (i >= N) break;
        int a = asso[i];
        if (a < 0) continue;
        float b = beta[i];
        unsigned mk = fkey(b);
        unsigned sk = ((const unsigned*)w)[a];
        float m = fdec(sk);
        float e = expf((b - m) * 1000.0f);
        int idx = a - cbase;
        if ((unsigned)idx < 512u) {
            if (mk == sk) atomicMax(&s_idx[idx], i);
            atomicAdd(&s_lse[idx], e);
        } else {
            if (mk == sk) atomicMax((int*)(w + 2 * K_CL) + a, i);
            atomicAdd(w + 5 * K_CL + a, e);
        }
    }
    __syncthreads();
    for (int j = t; j < 512; j += 256) {
        int a = cbase + j;
        if (a < K_CL) {
            if (s_idx[j] >= 0) atomicMax((int*)(w + 2 * K_CL) + a, s_idx[j]);
            if (s_lse[j] != 0.f) atomicAdd(w + 5 * K_CL + a, s_lse[j]);
        }
    }
}

// ---- P3: per-cluster alpha gather, beta penalty, row compaction ----
__global__ __launch_bounds__(1024) void k_p3(const float* __restrict__ beta,
                                             const float* __restrict__ coords,
                                             const int* __restrict__ rs,
                                             float* __restrict__ w) {
    int k = threadIdx.x;
    unsigned sk = ((unsigned*)w)[k];
    unsigned nk = ((unsigned*)(w + K_CL))[k];
    int aidx = ((int*)(w + 2 * K_CL))[k];
    bool ov = nk > 0u;
    int a = aidx > 0 ? aidx : 0;
    float x[8];
#pragma unroll
    for (int j = 0; j < 8; ++j) x[j] = coords[a * 8 + j];
    float ba = beta[a];
    float bca = fminf(fmaxf(ba, 0.f), 1.f - BETA_EPS_F);
    float ata = atanhf(bca);
    float qa = ov ? (ata * ata + Q_MIN_F) : 0.f;
    int rs1 = rs[1], rs2 = rs[2], rs3 = rs[3];
    int orr = (a >= rs1) + (a >= rs2) + (a >= rs3);
    float cf = qa / fmaxf((float)nk, 1.f);
    w[6 * K_CL + k] = qa;
    w[7 * K_CL + k] = cf;
    ((int*)(w + 8 * K_CL))[k] = orr;
    ((float4*)(w + 9 * K_CL))[k] = make_float4(x[0], x[1], x[2], x[3]);
    ((float4*)(w + 13 * K_CL))[k] = make_float4(x[4], x[5], x[6], x[7]);
    float m = ov ? fdec(sk) : 0.f;
    float lse = m + LSE_EPS_F * logf(w[5 * K_CL + k] + 1e-30f);
    float sb = fminf(fmaxf(w[3 * K_CL + k], 0.f), 1.f);
    float bpen = 1.f - lse + (1.f - sb);
    if (ov) {
        atomicAdd(w + ACC + 2 * B_RS + orr, 1.f);
        atomicAdd(w + ACC + 3 * B_RS + orr, bpen);
    }
    int key = ov ? orr : B_RS;
    __shared__ int wcnt[16][B_RS];
    __shared__ int woff[16][B_RS];
    __shared__ int rbase[B_RS + 1];
    int wv = k >> 6, ln = k & 63;
    unsigned long long myball = 0ULL;
#pragma unroll
    for (int r = 0; r < B_RS; ++r) {
        unsigned long long bl = __ballot(key == r);
        if (ln == 0) wcnt[wv][r] = __popcll(bl);
        if (key == r) myball = bl;
    }
    __syncthreads();
    if (k == 0) {
        int base = 0;
        for (int r = 0; r < B_RS; ++r) {
            rbase[r] = base;
            for (int wq = 0; wq < 16; ++wq) { woff[wq][r] = base; base += wcnt[wq][r]; }
        }
        rbase[B_RS] = base;
    }
    __syncthreads();
    if (key < B_RS) {
        int slot = woff[wv][key] + __popcll(myball & ((1ULL << ln) - 1ULL));
        // store -2*x and ck2+1e-6 so the inner loop is a pure fma chain
        ((float4*)(w + 17 * K_CL))[slot] = make_float4(-2.f * x[0], -2.f * x[1], -2.f * x[2], -2.f * x[3]);
        ((float4*)(w + 21 * K_CL))[slot] = make_float4(-2.f * x[4], -2.f * x[5], -2.f * x[6], -2.f * x[7]);
        float ck2 = 0.f;
#pragma unroll
        for (int j = 0; j < 8; ++j) ck2 += x[j] * x[j];
        ((float2*)(w + 25 * K_CL))[slot] = make_float2(ck2 + 1e-6f, cf);
    }
    if (k <= B_RS) ((int*)(w + 27 * K_CL))[k] = rbase[k];
}

// ---- P4: repulsion (tiled over cluster chunks), attraction, pl, outputs ----
__device__ __forceinline__ float rep_loop(int s, int e, float4 c0, float4 c1, float cn2,
                                          const float4* sx0, const float4* sx1,
                                          const float2* scc) {
    float acc = 0.f;
    for (int j = s; j < e; ++j) {
        float4 y0 = sx0[j];
        float4 y1 = sx1[j];
        float2 cx = scc[j];
        float d = cn2 + cx.x;
        d = fmaf(y0.x, c0.x, d); d = fmaf(y0.y, c0.y, d);
        d = fmaf(y0.z, c0.z, d); d = fmaf(y0.w, c0.w, d);
        d = fmaf(y1.x, c1.x, d); d = fmaf(y1.y, c1.y, d);
        d = fmaf(y1.z, c1.z, d); d = fmaf(y1.w, c1.w, d);
        d = fmaxf(d, 1e-6f);
        float v = fmaxf(1.f - sqrtf(d), 0.f);
        acc = fmaf(v, cx.y, acc);
    }
    return acc;
}

__global__ __launch_bounds__(256) void k_p4(const float* __restrict__ beta,
                                            const float* __restrict__ coords,
                                            const int* __restrict__ asso,
                                            const int* __restrict__ rs,
                                            float* __restrict__ w,
                                            float* __restrict__ out, int N) {
    __shared__ float4 sx0[256];
    __shared__ float4 sx1[256];
    __shared__ float2 scc[256];
    __shared__ float sa[B_RS], sr[B_RS];
    int t = threadIdx.x;
    int pc = blockIdx.x / CCH, cc = blockIdx.x % CCH;
    int base_i = pc * P4_PPB;
    int rs1 = rs[1], rs2 = rs[2], rs3 = rs[3];
    int lastp = min(base_i + P4_PPB, N) - 1;
    int r0 = (base_i >= rs1) + (base_i >= rs2) + (base_i >= rs3);
    int r1 = (lastp >= rs1) + (lastp >= rs2) + (lastp >= rs3);
    const int* rb = (const int*)(w + 27 * K_CL);
    int js0 = rb[r0], je0 = rb[r0 + 1];
    int L0 = (je0 - js0 + CCH - 1) / CCH;
    int a0s = js0 + cc * L0;
    int n0 = max(min(a0s + L0, je0) - a0s, 0);
    int n1 = 0, a1s = 0;
    if (r1 != r0) {
        int js1 = rb[r1], je1 = rb[r1 + 1];
        int L1 = (je1 - js1 + CCH - 1) / CCH;
        a1s = js1 + cc * L1;
        n1 = max(min(a1s + L1, je1) - a1s, 0);
    }
    if (t < B_RS) { sa[t] = 0.f; sr[t] = 0.f; }
    if (t < n0) {
        sx0[t] = ((const float4*)(w + 17 * K_CL))[a0s + t];
        sx1[t] = ((const float4*)(w + 21 * K_CL))[a0s + t];
        scc[t] = ((const float2*)(w + 25 * K_CL))[a0s + t];
    } else if (t - n0 < n1) {
        int j = t - n0;
        sx0[t] = ((const float4*)(w + 17 * K_CL))[a1s + j];
        sx1[t] = ((const float4*)(w + 21 * K_CL))[a1s + j];
        scc[t] = ((const float2*)(w + 25 * K_CL))[a1s + j];
    }
    __syncthreads();

    int i0 = base_i + 2 * t, i1 = i0 + 1;
    bool in0 = i0 < N, in1 = i1 < N;
    float b0 = 0.f, b1 = 0.f;
    int aa0 = -1, aa1 = -1;
    float4 c00, c01, c10, c11;
    float cn20 = 0.f, cn21 = 0.f;
    int rr0 = 0, rr1 = 0;
    if (in0) {
        const float4* cp = (const float4*)(coords + (size_t)i0 * 8);
        c00 = cp[0]; c01 = cp[1];
        cn20 = c00.x * c00.x + c00.y * c00.y + c00.z * c00.z + c00.w * c00.w +
               c01.x * c01.x + c01.y * c01.y + c01.z * c01.z + c01.w * c01.w;
        b0 = beta[i0]; aa0 = asso[i0];
        rr0 = (i0 >= rs1) + (i0 >= rs2) + (i0 >= rs3);
    }
    if (in1) {
        const float4* cp = (const float4*)(coords + (size_t)i1 * 8);
        c10 = cp[0]; c11 = cp[1];
        cn21 = c10.x * c10.x + c10.y * c10.y + c10.z * c10.z + c10.w * c10.w +
               c11.x * c11.x + c11.y * c11.y + c11.z * c11.z + c11.w * c11.w;
        b1 = beta[i1]; aa1 = asso[i1];
        rr1 = (i1 >= rs1) + (i1 >= rs2) + (i1 >= rs3);
    }
    int s0 = (rr0 == r0) ? 0 : n0, e0 = (rr0 == r0) ? n0 : n0 + n1;
    int s1 = (rr1 == r0) ? 0 : n0, e1 = (rr1 == r0) ? n0 : n0 + n1;
    float acc0 = 0.f, acc1 = 0.f;
    if (in0 && in1 && s0 == s1) {
        // fused: both points share the staged segment -> amortize LDS reads
        for (int j = s0; j < e0; ++j) {
            float4 y0 = sx0[j];
            float4 y1 = sx1[j];
            float2 cx = scc[j];
            float d0 = cn20 + cx.x, d1 = cn21 + cx.x;
            d0 = fmaf(y0.x, c00.x, d0); d1 = fmaf(y0.x, c10.x, d1);
            d0 = fmaf(y0.y, c00.y, d0); d1 = fmaf(y0.y, c10.y, d1);
            d0 = fmaf(y0.z, c00.z, d0); d1 = fmaf(y0.z, c10.z, d1);
            d0 = fmaf(y0.w, c00.w, d0); d1 = fmaf(y0.w, c10.w, d1);
            d0 = fmaf(y1.x, c01.x, d0); d1 = fmaf(y1.x, c11.x, d1);
            d0 = fmaf(y1.y, c01.y, d0); d1 = fmaf(y1.y, c11.y, d1);
            d0 = fmaf(y1.z, c01.z, d0); d1 = fmaf(y1.z, c11.z, d1);
            d0 = fmaf(y1.w, c01.w, d0); d1 = fmaf(y1.w, c11.w, d1);
            d0 = fmaxf(d0, 1e-6f); d1 = fmaxf(d1, 1e-6f);
            float v0 = fmaxf(1.f - sqrtf(d0), 0.f);
            float v1 = fmaxf(1.f - sqrtf(d1), 0.f);
            acc0 = fmaf(v0, cx.y, acc0);
            acc1 = fmaf(v1, cx.y, acc1);
        }
    } else {
        if (in0) acc0 = rep_loop(s0, e0, c00, c01, cn20, sx0, sx1, scc);
        if (in1) acc1 = rep_loop(s1, e1, c10, c11, cn21, sx0, sx1, scc);
    }

    // epilogue per point
#pragma unroll
    for (int p = 0; p < 2; ++p) {
        bool in = p ? in1 : in0;
        if (!in) continue;
        int i = p ? i1 : i0;
        float b = p ? b1 : b0;
        int aa = p ? aa1 : aa0;
        int r = p ? rr1 : rr0;
        float acc = p ? acc1 : acc0;
        float4 cA = p ? c10 : c00;
        float4 cB = p ? c11 : c01;
        float cn2 = p ? cn21 : cn20;
        float bc = fminf(fmaxf(b, 0.f), 1.f - BETA_EPS_F);
        float at = atanhf(bc);
        float at2 = at * at;
        float q = at2 + Q_MIN_F;
        float rep = q * acc;
        if (cc == 0) {
            bool valid = aa >= 0;
            int kk = valid ? aa : 0;
            float4 xk0 = ((const float4*)(w + 9 * K_CL))[kk];
            float4 xk1 = ((const float4*)(w + 13 * K_CL))[kk];
            float qak = w[6 * K_CL + kk];
            float d0 = cA.x - xk0.x, d1 = cA.y - xk0.y, d2 = cA.z - xk0.z, d3 = cA.w - xk0.w;
            float d4 = cB.x - xk1.x, d5 = cB.y - xk1.y, d6 = cB.z - xk1.z, d7 = cB.w - xk1.w;
            float dsq_att = d0 * d0 + d1 * d1 + d2 * d2 + d3 * d3 +
                            d4 * d4 + d5 * d5 + d6 * d6 + d7 * d7;
            float att = valid ? q * qak * dsq_att : 0.f;
            if (valid) {
                int ork = ((const int*)(w + 8 * K_CL))[kk];
                if (ork == r) {
                    float ck2 = xk0.x * xk0.x + xk0.y * xk0.y + xk0.z * xk0.z + xk0.w * xk0.w +
                                xk1.x * xk1.x + xk1.y * xk1.y + xk1.z * xk1.z + xk1.w * xk1.w;
                    float dotk = cA.x * xk0.x + cA.y * xk0.y + cA.z * xk0.z + cA.w * xk0.w +
                                 cB.x * xk1.x + cB.y * xk1.y + cB.z * xk1.z + cB.w * xk1.w;
                    float dsqk = fmaxf(cn2 + ck2 - 2.f * dotk, 0.f);
                    float vk = fmaxf(1.f - sqrtf(dsqk + 1e-6f), 0.f);
                    rep -= q * vk * w[7 * K_CL + kk];
                }
            }
            float psum = w[4 * K_CL + kk];
            float ocnt = w[ACC + 2 * B_RS + r];
            float pl = valid ? fmaxf(at2, 1e-6f) / fmaxf(psum, 1e-6f) : 0.f;
            pl = pl / fmaxf(ocnt, 1.f) * (1.f / B_RS);
            out[3 + i] = pl;
            atomicAdd(&out[3 + N + i], att + rep);
            atomicAdd(&sa[r], att);
        } else {
            atomicAdd(&out[3 + N + i], rep);
        }
        atomicAdd(&sr[r], rep);
    }
    __syncthreads();
    if (t < B_RS) {
        if (sa[t] != 0.f) atomicAdd(w + ACC + t, sa[t]);
        if (sr[t] != 0.f) atomicAdd(w + ACC + B_RS + t, sr[t]);
    }
}

__global__ void k_p5(const int* __restrict__ rs, const float* __restrict__ w,
                     float* __restrict__ out) {
    if (threadIdx.x == 0 && blockIdx.x == 0) {
        float lv = 0.f, lr = 0.f, lb = 0.f;
        for (int r = 0; r < B_RS; ++r) {
            float len = (float)(rs[r + 1] - rs[r]);
            lv += w[ACC + r] / len;
            lr += w[ACC + B_RS + r] / len;
            float oc = w[ACC + 2 * B_RS + r];
            float op = w[ACC + 3 * B_RS + r];
            float nc = w[ACC + 4 * B_RS + r];
            float ns = w[ACC + 5 * B_RS + r];
            lb += op / fmaxf(oc, 1.f) + S_B_F * (ns / fmaxf(nc, 1.f));
        }
        out[0] = lv * (1.f / B_RS);
        out[1] = lr * (1.f / B_RS);
        out[2] = lb * (1.f / B_RS);
    }
}

extern "C" void kernel_launch(void* const* d_in, const int* in_sizes, int n_in,
                              void* d_out, int out_size, void* d_ws, size_t ws_size,
                              hipStream_t stream) {
    const float* beta = (const float*)d_in[0];
    const float* coords = (const float*)d_in[1];
    const int* asso = (const int*)d_in[2];
    const int* rs = (const int*)d_in[3];
    int N = in_sizes[0];
    float* w = (float*)d_ws;
    float* out = (float*)d_out;
    int nb2 = (N + 511) / 512;
    hipLaunchKernelGGL(k_init, dim3(1), dim3(1024), 0, stream, w);
    hipMemsetAsync((void*)(out + 3 + N), 0, (size_t)N * sizeof(float), stream);
    hipLaunchKernelGGL(k_p1, dim3(nb2), dim3(256), 0, stream, beta, asso, rs, w, N);
    hipLaunchKernelGGL(k_p2, dim3(nb2), dim3(256), 0, stream, beta, asso, rs, w, N);
    hipLaunchKernelGGL(k_p3, dim3(1), dim3(1024), 0, stream, beta, coords, rs, w);
    hipLaunchKernelGGL(k_p4, dim3(nb2 * CCH), dim3(256), 0, stream, beta, coords, asso, rs, w, out, N);
    hipLaunchKernelGGL(k_p5, dim3(1), dim3(64), 0, stream, rs, w, out);
}

// Round 4
// 97.890 us; speedup vs baseline: 1.3440x; 1.0853x over previous
//
#include <hip/hip_runtime.h>

#define K_CL 1024
#define B_RS 4
#define CCH 4
#define PPB 512
#define Q_MIN_F 0.1f
#define S_B_F 1.0f
#define BETA_EPS_F 0.001f
#define LSE_EPS_F 0.001f

// scratch layout (float offsets)
#define O_KEY 0
#define O_NK  (1*K_CL)
#define O_SB  (3*K_CL)
#define O_PSM (4*K_CL)
#define O_QA  (6*K_CL)
#define O_CF  (7*K_CL)
#define O_OR  (8*K_CL)
#define O_XLO (9*K_CL)
#define O_XHI (13*K_CL)
#define O_CLO (17*K_CL)
#define O_CHI (21*K_CL)
#define O_CCK (25*K_CL)
#define O_RB  (27*K_CL)
#define O_ACC (27*K_CL+8)
// ACC: [0..4) obj_cnt, [4..8) obj_pen, [8..16) noise (cnt,sum interleaved by row)
#define O_RPK (27*K_CL+24)
#define O_RPN (O_RPK+8*K_CL)
#define O_RSB (O_RPN+8*K_CL)
#define O_RSP (O_RSB+8*K_CL)
#define O_RAI (O_RSP+8*K_CL)
#define O_RLS (O_RAI+8*K_CL)
#define O_QS  (O_RLS+8*K_CL)

__device__ __forceinline__ unsigned fkey(float f) {
    unsigned u = __float_as_uint(f);
    return ((int)u < 0) ? ~u : (u | 0x80000000u);
}
__device__ __forceinline__ float fdec(unsigned k) {
    unsigned u = ((int)k < 0) ? (k & 0x7fffffffu) : ~k;
    return __uint_as_float(u);
}

// ---- P1: per-point q/p, replicated segment atomics, noise bins ----
__global__ __launch_bounds__(256) void k_p1(const float* __restrict__ beta,
                                            const int* __restrict__ asso,
                                            const int* __restrict__ rs,
                                            float* __restrict__ w, int N) {
    __shared__ float ns[8];
    int t = threadIdx.x;
    if (t < 8) ns[t] = 0.f;
    int rs1 = rs[1], rs2 = rs[2], rs3 = rs[3];
    __syncthreads();
    int i0 = blockIdx.x * PPB + 2 * t;
    int rep = blockIdx.x & 7;
    bool in0 = i0 < N, in1 = i0 + 1 < N;
    float2 b2 = make_float2(0.f, 0.f);
    int2 a2 = make_int2(-1, -1);
    if (in1) { b2 = *(const float2*)(beta + i0); a2 = *(const int2*)(asso + i0); }
    else if (in0) { b2.x = beta[i0]; a2.x = asso[i0]; }
    float qv[2] = {0.f, 0.f}, pvv[2] = {0.f, 0.f};
#pragma unroll
    for (int p = 0; p < 2; ++p) {
        bool in = p ? in1 : in0;
        if (!in) continue;
        int i = i0 + p;
        float b = p ? b2.y : b2.x;
        int a = p ? a2.y : a2.x;
        float bc = fminf(fmaxf(b, 0.f), 1.f - BETA_EPS_F);
        float ath = 0.5f * __logf(__fdividef(1.f + bc, 1.f - bc));
        float at2 = ath * ath;
        qv[p] = at2 + Q_MIN_F;
        pvv[p] = fmaxf(at2, 1e-6f);
        if (a >= 0) {
            int idx = rep * K_CL + a;
            atomicMax((unsigned*)w + O_RPK + idx, fkey(b));
            atomicAdd((unsigned*)w + O_RPN + idx, 1u);
            atomicAdd(w + O_RSB + idx, b);
            atomicAdd(w + O_RSP + idx, pvv[p]);
        } else {
            int r = (i >= rs1) + (i >= rs2) + (i >= rs3);
            atomicAdd(&ns[r * 2], 1.f);
            atomicAdd(&ns[r * 2 + 1], b);
        }
    }
    float* qs = w + O_QS;
    float* ps = qs + N;
    if (in1) {
        *(float2*)(qs + i0) = make_float2(qv[0], qv[1]);
        *(float2*)(ps + i0) = make_float2(pvv[0], pvv[1]);
    } else if (in0) { qs[i0] = qv[0]; ps[i0] = pvv[0]; }
    __syncthreads();
    if (t < 8 && ns[t] != 0.f) atomicAdd(w + O_ACC + 8 + t, ns[t]);
}

// ---- M1: merge p1 replicas ----
__global__ __launch_bounds__(1024) void k_m1(float* __restrict__ w) {
    int k = threadIdx.x;
    unsigned key = 0u, cnt = 0u;
    float sb = 0.f, sp = 0.f;
#pragma unroll
    for (int r = 0; r < 8; ++r) {
        int idx = r * K_CL + k;
        unsigned kv = ((unsigned*)w)[O_RPK + idx];
        key = key > kv ? key : kv;
        cnt += ((unsigned*)w)[O_RPN + idx];
        sb += w[O_RSB + idx];
        sp += w[O_RSP + idx];
    }
    ((unsigned*)w)[O_KEY + k] = key;
    ((unsigned*)w)[O_NK + k] = cnt;
    w[O_SB + k] = sb;
    w[O_PSM + k] = sp;
}

// ---- P2: alpha idx + LSE sums (replicated) ----
__global__ __launch_bounds__(256) void k_p2(const float* __restrict__ beta,
                                            const int* __restrict__ asso,
                                            float* __restrict__ w, int N) {
    int t = threadIdx.x;
    int i0 = blockIdx.x * PPB + 2 * t;
    int rep = blockIdx.x & 7;
#pragma unroll
    for (int p = 0; p < 2; ++p) {
        int i = i0 + p;
        if (i >= N) break;
        int a = asso[i];
        if (a < 0) continue;
        float b = beta[i];
        unsigned mk = fkey(b);
        unsigned sk = ((const unsigned*)w)[O_KEY + a];
        if (mk == sk) atomicMax((int*)w + O_RAI + rep * K_CL + a, i);
        float m = fdec(sk);
        float e = __expf((b - m) * 1000.0f);
        atomicAdd(w + O_RLS + rep * K_CL + a, e);
    }
}

// ---- P3: merge p2 replicas, per-cluster pass, row compaction ----
__global__ __launch_bounds__(1024) void k_p3(const float* __restrict__ beta,
                                             const float* __restrict__ coords,
                                             const int* __restrict__ rs,
                                             float* __restrict__ w) {
    int k = threadIdx.x;
    int ai = 0; float ls = 0.f;
#pragma unroll
    for (int r = 0; r < 8; ++r) {
        int idx = r * K_CL + k;
        int av = ((int*)w)[O_RAI + idx];
        ai = ai > av ? ai : av;
        ls += w[O_RLS + idx];
    }
    unsigned sk = ((unsigned*)w)[O_KEY + k];
    unsigned nk = ((unsigned*)w)[O_NK + k];
    bool ov = nk > 0u;
    int a = ai;
    float x[8];
#pragma unroll
    for (int j = 0; j < 8; ++j) x[j] = coords[a * 8 + j];
    float ba = beta[a];
    float bca = fminf(fmaxf(ba, 0.f), 1.f - BETA_EPS_F);
    float ata = atanhf(bca);
    float qa = ov ? (ata * ata + Q_MIN_F) : 0.f;
    int rs1 = rs[1], rs2 = rs[2], rs3 = rs[3];
    int orr = (a >= rs1) + (a >= rs2) + (a >= rs3);
    float cf = qa / fmaxf((float)nk, 1.f);
    w[O_QA + k] = qa;
    w[O_CF + k] = cf;
    ((int*)w)[O_OR + k] = orr;
    ((float4*)(w + O_XLO))[k] = make_float4(x[0], x[1], x[2], x[3]);
    ((float4*)(w + O_XHI))[k] = make_float4(x[4], x[5], x[6], x[7]);
    float m = ov ? fdec(sk) : 0.f;
    float lse = m + LSE_EPS_F * logf(ls + 1e-30f);
    float sb = fminf(fmaxf(w[O_SB + k], 0.f), 1.f);
    float bpen = 1.f - lse + (1.f - sb);
    if (ov) {
        atomicAdd(w + O_ACC + orr, 1.f);
        atomicAdd(w + O_ACC + 4 + orr, bpen);
    }
    int key = ov ? orr : B_RS;
    __shared__ int wcnt[16][B_RS];
    __shared__ int woff[16][B_RS];
    __shared__ int rbase[B_RS + 1];
    int wv = k >> 6, ln = k & 63;
    unsigned long long myball = 0ULL;
#pragma unroll
    for (int r = 0; r < B_RS; ++r) {
        unsigned long long bl = __ballot(key == r);
        if (ln == 0) wcnt[wv][r] = __popcll(bl);
        if (key == r) myball = bl;
    }
    __syncthreads();
    if (k == 0) {
        int base = 0;
        for (int r = 0; r < B_RS; ++r) {
            rbase[r] = base;
            for (int wq = 0; wq < 16; ++wq) { woff[wq][r] = base; base += wcnt[wq][r]; }
        }
        rbase[B_RS] = base;
    }
    __syncthreads();
    if (key < B_RS) {
        int slot = woff[wv][key] + __popcll(myball & ((1ULL << ln) - 1ULL));
        ((float4*)(w + O_CLO))[slot] = make_float4(-2.f * x[0], -2.f * x[1], -2.f * x[2], -2.f * x[3]);
        ((float4*)(w + O_CHI))[slot] = make_float4(-2.f * x[4], -2.f * x[5], -2.f * x[6], -2.f * x[7]);
        float ck2 = 0.f;
#pragma unroll
        for (int j = 0; j < 8; ++j) ck2 += x[j] * x[j];
        ((float2*)(w + O_CCK))[slot] = make_float2(ck2 + 1e-6f, cf);
    }
    if (k <= B_RS) ((int*)w)[O_RB + k] = rbase[k];
}

// ---- P4: pure repulsion partials, no atomics, no epilogue ----
__device__ __forceinline__ float rep_loop(int s, int e, float4 c0, float4 c1, float cn2,
                                          const float4* sx0, const float4* sx1,
                                          const float2* scc) {
    float acc = 0.f;
    for (int j = s; j < e; ++j) {
        float4 y0 = sx0[j];
        float4 y1 = sx1[j];
        float2 cx = scc[j];
        float d = cn2 + cx.x;
        d = fmaf(y0.x, c0.x, d); d = fmaf(y0.y, c0.y, d);
        d = fmaf(y0.z, c0.z, d); d = fmaf(y0.w, c0.w, d);
        d = fmaf(y1.x, c1.x, d); d = fmaf(y1.y, c1.y, d);
        d = fmaf(y1.z, c1.z, d); d = fmaf(y1.w, c1.w, d);
        d = fmaxf(d, 1e-6f);
        float v = fmaxf(1.f - sqrtf(d), 0.f);
        acc = fmaf(v, cx.y, acc);
    }
    return acc;
}

__global__ __launch_bounds__(256) void k_p4(const float* __restrict__ coords,
                                            const int* __restrict__ rs,
                                            const float* __restrict__ w,
                                            float* __restrict__ repout, int N) {
    __shared__ float4 sx0[128];
    __shared__ float4 sx1[128];
    __shared__ float2 scc[128];
    int t = threadIdx.x;
    int pc = blockIdx.x / CCH, cc = blockIdx.x % CCH;
    int base_i = pc * PPB;
    int rs1 = rs[1], rs2 = rs[2], rs3 = rs[3];
    int lastp = min(base_i + PPB, N) - 1;
    int r0 = (base_i >= rs1) + (base_i >= rs2) + (base_i >= rs3);
    int r1 = (lastp >= rs1) + (lastp >= rs2) + (lastp >= rs3);
    const int* rb = (const int*)w + O_RB;
    int js0 = rb[r0], je0 = rb[r0 + 1];
    int L0 = (je0 - js0 + CCH - 1) / CCH;
    int a0s = js0 + cc * L0;
    int n0 = max(min(a0s + L0, je0) - a0s, 0);
    int n1 = 0, a1s = 0;
    if (r1 != r0) {
        int js1 = rb[r1], je1 = rb[r1 + 1];
        int L1 = (je1 - js1 + CCH - 1) / CCH;
        a1s = js1 + cc * L1;
        n1 = max(min(a1s + L1, je1) - a1s, 0);
    }
    if (t < n0) {
        sx0[t] = ((const float4*)(w + O_CLO))[a0s + t];
        sx1[t] = ((const float4*)(w + O_CHI))[a0s + t];
        scc[t] = ((const float2*)(w + O_CCK))[a0s + t];
    } else if (t - n0 < n1) {
        int j = t - n0;
        sx0[t] = ((const float4*)(w + O_CLO))[a1s + j];
        sx1[t] = ((const float4*)(w + O_CHI))[a1s + j];
        scc[t] = ((const float2*)(w + O_CCK))[a1s + j];
    }
    __syncthreads();
    int i0 = base_i + 2 * t, i1 = i0 + 1;
    bool in0 = i0 < N, in1 = i1 < N;
    float4 c00, c01, c10, c11;
    float cn20 = 0.f, cn21 = 0.f;
    int rr0 = r0, rr1 = r0;
    if (in0) {
        const float4* cp = (const float4*)(coords + (size_t)i0 * 8);
        c00 = cp[0]; c01 = cp[1];
        cn20 = c00.x * c00.x + c00.y * c00.y + c00.z * c00.z + c00.w * c00.w +
               c01.x * c01.x + c01.y * c01.y + c01.z * c01.z + c01.w * c01.w;
        rr0 = (i0 >= rs1) + (i0 >= rs2) + (i0 >= rs3);
    }
    if (in1) {
        const float4* cp = (const float4*)(coords + (size_t)i1 * 8);
        c10 = cp[0]; c11 = cp[1];
        cn21 = c10.x * c10.x + c10.y * c10.y + c10.z * c10.z + c10.w * c10.w +
               c11.x * c11.x + c11.y * c11.y + c11.z * c11.z + c11.w * c11.w;
        rr1 = (i1 >= rs1) + (i1 >= rs2) + (i1 >= rs3);
    }
    int s0 = (rr0 == r0) ? 0 : n0, e0 = (rr0 == r0) ? n0 : n0 + n1;
    int s1 = (rr1 == r0) ? 0 : n0, e1 = (rr1 == r0) ? n0 : n0 + n1;
    float acc0 = 0.f, acc1 = 0.f;
    if (in0 && in1 && s0 == s1) {
#pragma unroll 2
        for (int j = s0; j < e0; ++j) {
            float4 y0 = sx0[j];
            float4 y1 = sx1[j];
            float2 cx = scc[j];
            float d0 = cn20 + cx.x, d1 = cn21 + cx.x;
            d0 = fmaf(y0.x, c00.x, d0); d1 = fmaf(y0.x, c10.x, d1);
            d0 = fmaf(y0.y, c00.y, d0); d1 = fmaf(y0.y, c10.y, d1);
            d0 = fmaf(y0.z, c00.z, d0); d1 = fmaf(y0.z, c10.z, d1);
            d0 = fmaf(y0.w, c00.w, d0); d1 = fmaf(y0.w, c10.w, d1);
            d0 = fmaf(y1.x, c01.x, d0); d1 = fmaf(y1.x, c11.x, d1);
            d0 = fmaf(y1.y, c01.y, d0); d1 = fmaf(y1.y, c11.y, d1);
            d0 = fmaf(y1.z, c01.z, d0); d1 = fmaf(y1.z, c11.z, d1);
            d0 = fmaf(y1.w, c01.w, d0); d1 = fmaf(y1.w, c11.w, d1);
            d0 = fmaxf(d0, 1e-6f); d1 = fmaxf(d1, 1e-6f);
            float v0 = fmaxf(1.f - sqrtf(d0), 0.f);
            float v1 = fmaxf(1.f - sqrtf(d1), 0.f);
            acc0 = fmaf(v0, cx.y, acc0);
            acc1 = fmaf(v1, cx.y, acc1);
        }
    } else {
        if (in0) acc0 = rep_loop(s0, e0, c00, c01, cn20, sx0, sx1, scc);
        if (in1) acc1 = rep_loop(s1, e1, c10, c11, cn21, sx0, sx1, scc);
    }
    float* ro = repout + (size_t)cc * N;
    if (in1) *(float2*)(ro + i0) = make_float2(acc0, acc1);
    else if (in0) ro[i0] = acc0;
}

// ---- P6: combine partials, attraction, own-term, pl, outputs, row sums ----
__global__ __launch_bounds__(256) void k_p6(const float* __restrict__ coords,
                                            const int* __restrict__ asso,
                                            const int* __restrict__ rs,
                                            const float* __restrict__ w,
                                            const float* __restrict__ repin,
                                            float* __restrict__ p6p,
                                            float* __restrict__ out, int N) {
    __shared__ float sar[8];
    int t = threadIdx.x;
    if (t < 8) sar[t] = 0.f;
    int rs1 = rs[1], rs2 = rs[2], rs3 = rs[3];
    __syncthreads();
    int i0 = blockIdx.x * PPB + 2 * t;
    const float* qs = w + O_QS;
    const float* ps = qs + N;
    float attv[2] = {0.f, 0.f}, repv[2] = {0.f, 0.f};
    int rv[2];
    float2 rc[4];
    bool in1g = i0 + 1 < N;
    if (in1g) {
#pragma unroll
        for (int s = 0; s < 4; ++s) rc[s] = *(const float2*)(repin + (size_t)s * N + i0);
    }
#pragma unroll
    for (int p = 0; p < 2; ++p) {
        int i = i0 + p;
        int ic = min(i, N - 1);
        int r = (ic >= rs1) + (ic >= rs2) + (ic >= rs3);
        rv[p] = r;
        if (i >= N) continue;
        float q = qs[i], pv = ps[i];
        int a = asso[i];
        bool valid = a >= 0;
        int kk = valid ? a : 0;
        float racc;
        if (in1g) racc = p ? (rc[0].y + rc[1].y + rc[2].y + rc[3].y)
                           : (rc[0].x + rc[1].x + rc[2].x + rc[3].x);
        else racc = repin[i] + repin[N + i] + repin[2 * (size_t)N + i] + repin[3 * (size_t)N + i];
        const float4* cp = (const float4*)(coords + (size_t)i * 8);
        float4 c0 = cp[0], c1 = cp[1];
        float att = 0.f;
        if (valid) {
            float4 xk0 = ((const float4*)(w + O_XLO))[kk];
            float4 xk1 = ((const float4*)(w + O_XHI))[kk];
            float qak = w[O_QA + kk];
            float d0 = c0.x - xk0.x, d1 = c0.y - xk0.y, d2 = c0.z - xk0.z, d3 = c0.w - xk0.w;
            float d4 = c1.x - xk1.x, d5 = c1.y - xk1.y, d6 = c1.z - xk1.z, d7 = c1.w - xk1.w;
            float dsq = d0 * d0 + d1 * d1 + d2 * d2 + d3 * d3 +
                        d4 * d4 + d5 * d5 + d6 * d6 + d7 * d7;
            att = q * qak * dsq;
            int ork = ((const int*)w)[O_OR + kk];
            if (ork == r) {
                float cn2 = c0.x * c0.x + c0.y * c0.y + c0.z * c0.z + c0.w * c0.w +
                            c1.x * c1.x + c1.y * c1.y + c1.z * c1.z + c1.w * c1.w;
                float ck2 = xk0.x * xk0.x + xk0.y * xk0.y + xk0.z * xk0.z + xk0.w * xk0.w +
                            xk1.x * xk1.x + xk1.y * xk1.y + xk1.z * xk1.z + xk1.w * xk1.w;
                float dotk = c0.x * xk0.x + c0.y * xk0.y + c0.z * xk0.z + c0.w * xk0.w +
                             c1.x * xk1.x + c1.y * xk1.y + c1.z * xk1.z + c1.w * xk1.w;
                float d = fmaxf(cn2 + ck2 - 2.f * dotk, 0.f) + 1e-6f;
                float vk = fmaxf(1.f - sqrtf(d), 0.f);
                racc -= vk * w[O_CF + kk];
            }
        }
        float rp = q * racc;
        attv[p] = att; repv[p] = rp;
        float psum = w[O_PSM + kk];
        float ocnt = w[O_ACC + r];
        float pl = valid ? pv / fmaxf(psum, 1e-6f) / fmaxf(ocnt, 1.f) * 0.25f : 0.f;
        out[3 + i] = pl;
        out[3 + N + i] = att + rp;
    }
    // row reduction: wave-level shfl, LDS atomic only once per wave
    int lane = t & 63;
    int rA = __shfl(rv[0], 0);
    bool uni = __all(rv[0] == rA) && __all(rv[1] == rA);
    if (uni) {
        float aS = attv[0] + attv[1], rS = repv[0] + repv[1];
#pragma unroll
        for (int o = 32; o; o >>= 1) { aS += __shfl_xor(aS, o); rS += __shfl_xor(rS, o); }
        if (lane == 0) { atomicAdd(&sar[rA * 2], aS); atomicAdd(&sar[rA * 2 + 1], rS); }
    } else {
#pragma unroll
        for (int p = 0; p < 2; ++p) {
            if (i0 + p < N) {
                atomicAdd(&sar[rv[p] * 2], attv[p]);
                atomicAdd(&sar[rv[p] * 2 + 1], repv[p]);
            }
        }
    }
    __syncthreads();
    if (t < 8) p6p[blockIdx.x * 8 + t] = sar[t];
}

// ---- P5: final scalars ----
__global__ __launch_bounds__(256) void k_p5(const int* __restrict__ rs,
                                            const float* __restrict__ w,
                                            const float* __restrict__ p6p, int nb,
                                            float* __restrict__ out) {
    __shared__ float red[8][33];
    int t = threadIdx.x;
    int slot = t & 7, j0 = t >> 3;
    float acc = 0.f;
    for (int j = j0; j < nb; j += 32) acc += p6p[j * 8 + slot];
    red[slot][j0] = acc;
    __syncthreads();
    if (t == 0) {
        float lv = 0.f, lr = 0.f, lb = 0.f;
        for (int r = 0; r < B_RS; ++r) {
            float a = 0.f, rp = 0.f;
            for (int j = 0; j < 32; ++j) { a += red[r * 2][j]; rp += red[r * 2 + 1][j]; }
            float len = (float)(rs[r + 1] - rs[r]);
            lv += a / len;
            lr += rp / len;
            float oc = w[O_ACC + r], op = w[O_ACC + 4 + r];
            float nc = w[O_ACC + 8 + 2 * r], nsm = w[O_ACC + 9 + 2 * r];
            lb += op / fmaxf(oc, 1.f) + S_B_F * (nsm / fmaxf(nc, 1.f));
        }
        out[0] = lv * 0.25f;
        out[1] = lr * 0.25f;
        out[2] = lb * 0.25f;
    }
}

extern "C" void kernel_launch(void* const* d_in, const int* in_sizes, int n_in,
                              void* d_out, int out_size, void* d_ws, size_t ws_size,
                              hipStream_t stream) {
    const float* beta = (const float*)d_in[0];
    const float* coords = (const float*)d_in[1];
    const int* asso = (const int*)d_in[2];
    const int* rs = (const int*)d_in[3];
    int N = in_sizes[0];
    float* w = (float*)d_ws;
    float* out = (float*)d_out;
    int nb = (N + PPB - 1) / PPB;
    float* p6p = w + O_QS + 2 * (size_t)N;
    float* repb = p6p + 8 * (size_t)nb;
    (void)hipMemsetAsync((void*)(w + O_ACC), 0, (size_t)(O_QS - O_ACC) * sizeof(float), stream);
    hipLaunchKernelGGL(k_p1, dim3(nb), dim3(256), 0, stream, beta, asso, rs, w, N);
    hipLaunchKernelGGL(k_m1, dim3(1), dim3(1024), 0, stream, w);
    hipLaunchKernelGGL(k_p2, dim3(nb), dim3(256), 0, stream, beta, asso, w, N);
    hipLaunchKernelGGL(k_p3, dim3(1), dim3(1024), 0, stream, beta, coords, rs, w);
    hipLaunchKernelGGL(k_p4, dim3(nb * CCH), dim3(256), 0, stream, coords, rs, w, repb, N);
    hipLaunchKernelGGL(k_p6, dim3(nb), dim3(256), 0, stream, coords, asso, rs, w, repb, p6p, out, N);
    hipLaunchKernelGGL(k_p5, dim3(1), dim3(256), 0, stream, rs, w, p6p, nb, out);
}